// Round 5
// baseline (445.792 us; speedup 1.0000x reference)
//
#include <hip/hip_runtime.h>
#include <cstdint>

// CausalSelfAttention fused pipeline, all-bf16 MFMA path.
// Phases: [x->bf16 swz] [W^T->bf16 swz] -> QKV GEMM -> flash attn -> out GEMM.
// attn is BARRIER-FREE: K and V^T fragments read directly from global (L2-resident,
// m169 regime); only wave-private P-transpose LDS remains. K plain [s][d];
// V stored transposed (Vt[b,h][d][s]).
// ws layout (ushort elems): Q[8.39M] K[8.39M] Vt[8.39M] AO[8.39M] Xb[8.39M] WtQ[786K] WtO[262K]

#define DEVI __device__ __forceinline__

typedef __bf16 bf8 __attribute__((ext_vector_type(8)));
typedef float f4 __attribute__((ext_vector_type(4)));
typedef unsigned short us8 __attribute__((ext_vector_type(8)));
typedef unsigned short us4 __attribute__((ext_vector_type(4)));

typedef const unsigned int __attribute__((address_space(1))) gu32;
typedef unsigned int __attribute__((address_space(3))) lu32;

DEVI unsigned short f2bf(float f) {  // RNE f32->bf16 (no NaN inputs here)
  unsigned u = __builtin_bit_cast(unsigned, f);
  u += 0x7fffu + ((u >> 16) & 1u);
  return (unsigned short)(u >> 16);
}

DEVI void gl_lds16(const void* g, void* l) {
  // async global->LDS, 16B/lane, dest = wave-uniform base + lane*16
  __builtin_amdgcn_global_load_lds((gu32*)g, (lu32*)l, 16, 0, 0);
}

DEVI bf8 comb(us4 a, us4 b) {
  us8 r;
  r[0]=a[0]; r[1]=a[1]; r[2]=a[2]; r[3]=a[3];
  r[4]=b[0]; r[5]=b[1]; r[6]=b[2]; r[7]=b[3];
  return __builtin_bit_cast(bf8, r);
}

// ---------------- prep: x (f32 [16384][512]) -> bf16, chunk-swizzled ----------------
// storage: within each row, 16B chunk c stored at (c&~7)|((c&7)^(row&7))
__global__ __launch_bounds__(256) void k_convert_x(const float* __restrict__ x,
                                                   unsigned short* __restrict__ xb) {
  int c = blockIdx.x * 256 + threadIdx.x;   // 1,048,576 chunks
  int row = c >> 6, cl = c & 63;
  const float* s = x + ((size_t)row << 9) + (cl << 3);
  float4 a = *(const float4*)s;
  float4 b = *(const float4*)(s + 4);
  us8 o;
  o[0]=f2bf(a.x); o[1]=f2bf(a.y); o[2]=f2bf(a.z); o[3]=f2bf(a.w);
  o[4]=f2bf(b.x); o[5]=f2bf(b.y); o[6]=f2bf(b.z); o[7]=f2bf(b.w);
  int p = (cl & ~7) | ((cl & 7) ^ (row & 7));
  *(us8*)(xb + ((size_t)row << 9) + (p << 3)) = o;
}

// ------------- prep: W [512][N] f32 -> Wt [N][512] bf16, chunk-swizzled -------------
__global__ __launch_bounds__(256) void k_transpose_w(const float* __restrict__ W,
                                                     unsigned short* __restrict__ Wt, int N) {
  __shared__ float t[32][33];
  int k0 = blockIdx.x * 32, n0 = blockIdx.y * 32;
  int tx = threadIdx.x & 31, ty = threadIdx.x >> 5;
#pragma unroll
  for (int r = 0; r < 4; ++r)
    t[ty + r * 8][tx] = W[(size_t)(k0 + ty + r * 8) * N + n0 + tx];
  __syncthreads();
#pragma unroll
  for (int r = 0; r < 4; ++r) {
    int n = n0 + ty + r * 8, k = k0 + tx;
    int k2 = (k & ~63) | ((((k >> 3) & 7) ^ (n & 7)) << 3) | (k & 7);
    Wt[((size_t)n << 9) + k2] = f2bf(t[tx][ty + r * 8]);
  }
}

// ---------------- GEMM: C[M][col] = A[M][512] * Bt[col][512]^T + bias ----------------
// 128x128 tile, BK=64, 4 waves (2x2), each wave 64x64 via 4x4 16x16x32 mfma frags.
// EPI=0: QKV epilogue (scale Q by 0.125; K plain [b,h,s,d]; V transposed [b,h,d,s])
// EPI=1: f32 out + bias
template <int EPI>
__global__ __launch_bounds__(256, 2)
void k_gemm(const unsigned short* __restrict__ Ag, const unsigned short* __restrict__ Bg,
            const float* __restrict__ bias, float* __restrict__ Of,
            unsigned short* __restrict__ Oq, unsigned short* __restrict__ Ok,
            unsigned short* __restrict__ Ov) {
  __shared__ __align__(16) unsigned short lds[128 * 64 * 2];
  unsigned short* Al = lds;
  unsigned short* Bl = lds + 128 * 64;
  const int tid = threadIdx.x, wv = tid >> 6, lane = tid & 63, g = lane >> 4, cl = lane & 15;
  const int wm = wv >> 1, wn = wv & 1;
  const int row0 = blockIdx.x * 128, col0 = blockIdx.y * 128;
  f4 acc[4][4];
#pragma unroll
  for (int i = 0; i < 4; ++i)
#pragma unroll
    for (int j = 0; j < 4; ++j) acc[i][j] = (f4){0.f, 0.f, 0.f, 0.f};

  for (int kt = 0; kt < 8; ++kt) {
#pragma unroll
    for (int j = 0; j < 4; ++j) {
      int ci = wv * 4 + j;
      int gci = ci * 64 + lane;
      int r = gci >> 3, cc = gci & 7;
      gl_lds16(Ag + ((size_t)(row0 + r) << 9) + kt * 64 + cc * 8, Al + ci * 512);
      gl_lds16(Bg + ((size_t)(col0 + r) << 9) + kt * 64 + cc * 8, Bl + ci * 512);
    }
    __syncthreads();
#pragma unroll
    for (int kk = 0; kk < 2; ++kk) {
      bf8 af[4], bb[4];
#pragma unroll
      for (int mf = 0; mf < 4; ++mf) {
        int r = wm * 64 + mf * 16 + cl;
        int cc = (kk * 4 + g) ^ (r & 7);
        af[mf] = *(const bf8*)(Al + r * 64 + cc * 8);
      }
#pragma unroll
      for (int nf = 0; nf < 4; ++nf) {
        int r = wn * 64 + nf * 16 + cl;
        int cc = (kk * 4 + g) ^ (r & 7);
        bb[nf] = *(const bf8*)(Bl + r * 64 + cc * 8);
      }
#pragma unroll
      for (int mf = 0; mf < 4; ++mf)
#pragma unroll
        for (int nf = 0; nf < 4; ++nf)
          acc[mf][nf] = __builtin_amdgcn_mfma_f32_16x16x32_bf16(af[mf], bb[nf], acc[mf][nf], 0, 0, 0);
    }
    __syncthreads();
  }

#pragma unroll
  for (int nf = 0; nf < 4; ++nf) {
    int col = col0 + wn * 64 + nf * 16 + cl;
    float bv = bias[col];
#pragma unroll
    for (int mf = 0; mf < 4; ++mf) {
#pragma unroll
      for (int j = 0; j < 4; ++j) {
        int row = row0 + wm * 64 + mf * 16 + 4 * g + j;   // C/D: col=lane&15, row=4*(lane>>4)+reg
        float v = acc[mf][nf][j] + bv;
        if (EPI == 1) {
          Of[((size_t)row << 9) + col] = v;
        } else {
          int which = col >> 9, h = (col >> 6) & 7, d = col & 63;
          int b = row >> 11, s = row & 2047;
          if (which == 0) {
            Oq[(((size_t)b * 8 + h) * 2048 + s) * 64 + d] = f2bf(v * 0.125f);  // fold scale
          } else if (which == 1) {
            Ok[(((size_t)b * 8 + h) * 2048 + s) * 64 + d] = f2bf(v);           // plain [s][d]
          } else {
            Ov[(((size_t)b * 8 + h) * 64 + d) * 2048 + s] = f2bf(v);           // transposed V
          }
        }
      }
    }
  }
}

// ------------------------------- flash attention --------------------------------
// block = (b, h, 64-row q tile); 4 waves x 16 q rows, fully independent (NO barriers).
// K and V^T fragments read directly from global (L1/L2-served, 16B aligned).
// Only LDS: per-wave P-transpose buffer (same-wave DS ordering, no barrier).
__global__ __launch_bounds__(256, 2)
void k_attn(const unsigned short* __restrict__ Q, const unsigned short* __restrict__ K,
            const unsigned short* __restrict__ Vt, const float* __restrict__ rel,
            unsigned short* __restrict__ AO) {
  __shared__ __align__(16) unsigned short Pl[4][16 * 68];
  const int tid = threadIdx.x, wv = tid >> 6, lane = tid & 63, g = lane >> 4, cl = lane & 15;
  // block-id swizzle: 8 batches sharing a rel_pos panel land on one XCD (bid%8 const)
  int bid = blockIdx.x;
  int glo = bid & 7, rest = bid >> 3;
  int b = rest & 7, ghi = rest >> 3;
  int grp = ghi * 8 + glo;
  int h = grp >> 5, qt = 31 - (grp & 31);        // big-first: long blocks dispatch early
  int qb = qt << 6;
  size_t bhoff = (((size_t)b << 3) + h) * (size_t)(2048 * 64);
  const unsigned short* Qp = Q + bhoff;
  const unsigned short* Kp = K + bhoff;
  const unsigned short* Vp = Vt + bhoff;   // [d][s] layout
  const float* relp = rel + ((size_t)h << 22);
  const int qrb = qb + wv * 16;

  bf8 qf[2];
#pragma unroll
  for (int kk = 0; kk < 2; ++kk)
    qf[kk] = *(const bf8*)(Qp + ((size_t)(qrb + cl) << 6) + kk * 32 + g * 8);

  f4 oa[4];
  float mrun[4], lrun[4];
#pragma unroll
  for (int j = 0; j < 4; ++j) { mrun[j] = -1e30f; lrun[j] = 0.f; }
#pragma unroll
  for (int ct = 0; ct < 4; ++ct) oa[ct] = (f4){0.f, 0.f, 0.f, 0.f};

  unsigned short* pw = Pl[wv];

  for (int kt = 0; kt <= qt; ++kt) {
    int kb = kt << 6;
    // ---- issue ALL loads for this tile up front (independent; counted-vmcnt) ----
    bf8 kf[2][4], vf[2][4];
#pragma unroll
    for (int kk = 0; kk < 2; ++kk)
#pragma unroll
      for (int ct = 0; ct < 4; ++ct) {
        kf[kk][ct] = *(const bf8*)(Kp + ((size_t)(kb + ct * 16 + cl) << 6) + kk * 32 + g * 8);
        vf[kk][ct] = *(const bf8*)(Vp + ((size_t)(ct * 16 + cl) << 11) + kb + kk * 32 + g * 8);
      }
    float rl[4][4];
    const float* rb = relp + ((size_t)(qrb + 4 * g) << 11) + kb + cl;
#pragma unroll
    for (int ct = 0; ct < 4; ++ct)
#pragma unroll
      for (int j = 0; j < 4; ++j)
        rl[ct][j] = rb[(j << 11) + ct * 16];

    // ---- QK^T ----
    f4 sa[4];
#pragma unroll
    for (int ct = 0; ct < 4; ++ct) sa[ct] = (f4){0.f, 0.f, 0.f, 0.f};
#pragma unroll
    for (int kk = 0; kk < 2; ++kk)
#pragma unroll
      for (int ct = 0; ct < 4; ++ct)
        sa[ct] = __builtin_amdgcn_mfma_f32_16x16x32_bf16(qf[kk], kf[kk][ct], sa[ct], 0, 0, 0);

    // rel_pos; causal mask only on the diagonal tile (interior: kcol<qb<=qrow always)
    if (kt == qt) {
#pragma unroll
      for (int ct = 0; ct < 4; ++ct) {
        int kcol = kb + ct * 16 + cl;
#pragma unroll
        for (int j = 0; j < 4; ++j) {
          int qrow = qrb + 4 * g + j;
          float sv = sa[ct][j] + rl[ct][j];
          sa[ct][j] = (kcol > qrow) ? -1e30f : sv;
        }
      }
    } else {
#pragma unroll
      for (int ct = 0; ct < 4; ++ct)
#pragma unroll
        for (int j = 0; j < 4; ++j) sa[ct][j] += rl[ct][j];
    }
    // wave-parallel online softmax (rows live in 16-lane groups)
    float al[4], mx[4];
#pragma unroll
    for (int j = 0; j < 4; ++j) {
      float m0 = fmaxf(fmaxf(sa[0][j], sa[1][j]), fmaxf(sa[2][j], sa[3][j]));
      m0 = fmaxf(m0, __shfl_xor(m0, 1, 16));
      m0 = fmaxf(m0, __shfl_xor(m0, 2, 16));
      m0 = fmaxf(m0, __shfl_xor(m0, 4, 16));
      m0 = fmaxf(m0, __shfl_xor(m0, 8, 16));
      float mn = fmaxf(mrun[j], m0);
      al[j] = __expf(mrun[j] - mn);
      mrun[j] = mn;
      mx[j] = mn;
    }
#pragma unroll
    for (int ct = 0; ct < 4; ++ct)
#pragma unroll
      for (int j = 0; j < 4; ++j) sa[ct][j] = __expf(sa[ct][j] - mx[j]);
#pragma unroll
    for (int j = 0; j < 4; ++j) {
      float rs = sa[0][j] + sa[1][j] + sa[2][j] + sa[3][j];
      rs += __shfl_xor(rs, 1, 16);
      rs += __shfl_xor(rs, 2, 16);
      rs += __shfl_xor(rs, 4, 16);
      rs += __shfl_xor(rs, 8, 16);
      lrun[j] = lrun[j] * al[j] + rs;
    }
#pragma unroll
    for (int ct = 0; ct < 4; ++ct) {
      oa[ct][0] *= al[0]; oa[ct][1] *= al[1]; oa[ct][2] *= al[2]; oa[ct][3] *= al[3];
    }
    // P -> bf16 -> per-wave LDS transpose (write C-layout, read A-layout).
    // Same-wave DS ops are in-order; no barrier needed.
#pragma unroll
    for (int ct = 0; ct < 4; ++ct)
#pragma unroll
      for (int j = 0; j < 4; ++j)
        pw[(4 * g + j) * 68 + ct * 16 + cl] = f2bf(sa[ct][j]);
    // PV: A = P[q=cl][k=kk*32+g*8+j], B = Vt frags loaded at top
#pragma unroll
    for (int kk = 0; kk < 2; ++kk) {
      us4 p0 = *(const us4*)(pw + cl * 68 + kk * 32 + g * 8);
      us4 p1 = *(const us4*)(pw + cl * 68 + kk * 32 + g * 8 + 4);
      bf8 pf = comb(p0, p1);
#pragma unroll
      for (int ct = 0; ct < 4; ++ct)
        oa[ct] = __builtin_amdgcn_mfma_f32_16x16x32_bf16(pf, vf[kk][ct], oa[ct], 0, 0, 0);
    }
  }
  // epilogue: O /= l, write bf16 [b][s][h*64+d] with chunk swizzle for out-GEMM staging
#pragma unroll
  for (int j = 0; j < 4; ++j) {
    float inv = 1.0f / lrun[j];
    int s = qrb + 4 * g + j;
#pragma unroll
    for (int ct = 0; ct < 4; ++ct) {
      int d = ct * 16 + cl;
      int d2 = (d & 7) | (((d >> 3) ^ (s & 7)) << 3);
      AO[(((size_t)b << 11) + s) * 512 + h * 64 + d2] = f2bf(oa[ct][j] * inv);
    }
  }
}

// ------------------------------------ launch ------------------------------------
extern "C" void kernel_launch(void* const* d_in, const int* in_sizes, int n_in,
                              void* d_out, int out_size, void* d_ws, size_t ws_size,
                              hipStream_t stream) {
  const float* x    = (const float*)d_in[0];
  const float* Wqkv = (const float*)d_in[1];
  const float* bqkv = (const float*)d_in[2];
  const float* Wout = (const float*)d_in[3];
  const float* bout = (const float*)d_in[4];
  const float* rel  = (const float*)d_in[5];
  float* out = (float*)d_out;

  unsigned short* Qw  = (unsigned short*)d_ws;
  unsigned short* Kw  = Qw  + 8388608;
  unsigned short* Vw  = Kw  + 8388608;
  unsigned short* AOw = Vw  + 8388608;
  unsigned short* Xb  = AOw + 8388608;
  unsigned short* WtQ = Xb  + 8388608;
  unsigned short* WtO = WtQ + 786432;

  k_convert_x<<<dim3(4096), dim3(256), 0, stream>>>(x, Xb);
  k_transpose_w<<<dim3(16, 48), dim3(256), 0, stream>>>(Wqkv, WtQ, 1536);
  k_transpose_w<<<dim3(16, 16), dim3(256), 0, stream>>>(Wout, WtO, 512);
  k_gemm<0><<<dim3(128, 12), dim3(256), 0, stream>>>(Xb, WtQ, bqkv, nullptr, Qw, Kw, Vw);
  k_attn<<<dim3(2048), dim3(256), 0, stream>>>(Qw, Kw, Vw, rel, AOw);
  k_gemm<1><<<dim3(128, 4), dim3(256), 0, stream>>>(AOw, WtO, bout, out, nullptr, nullptr, nullptr);
}

// Round 6
// 243.062 us; speedup vs baseline: 1.8341x; 1.8341x over previous
//
#include <hip/hip_runtime.h>
#include <cstdint>

// CausalSelfAttention fused pipeline, all-bf16 MFMA path.
// Q/K/V are stored in MFMA-FRAGMENT ORDER so every attn fragment load is
// base + lane*16B (fully coalesced, 8 cache lines per 1KB load) — R5's
// lesson: strided per-lane gathers saturate L1 line-transaction throughput.
// attn is barrier-free; only wave-private P-transpose LDS remains.
// ws layout (ushort elems): Qf[8.39M] Kf[8.39M] Vf[8.39M] AO[8.39M] Xb[8.39M] WtQ[786K] WtO[262K]

#define DEVI __device__ __forceinline__

typedef __bf16 bf8 __attribute__((ext_vector_type(8)));
typedef float f4 __attribute__((ext_vector_type(4)));
typedef unsigned short us8 __attribute__((ext_vector_type(8)));
typedef unsigned short us4 __attribute__((ext_vector_type(4)));

typedef const unsigned int __attribute__((address_space(1))) gu32;
typedef unsigned int __attribute__((address_space(3))) lu32;

DEVI unsigned short f2bf(float f) {  // RNE f32->bf16 (no NaN inputs here)
  unsigned u = __builtin_bit_cast(unsigned, f);
  u += 0x7fffu + ((u >> 16) & 1u);
  return (unsigned short)(u >> 16);
}

DEVI void gl_lds16(const void* g, void* l) {
  // async global->LDS, 16B/lane, dest = wave-uniform base + lane*16
  __builtin_amdgcn_global_load_lds((gu32*)g, (lu32*)l, 16, 0, 0);
}

DEVI bf8 comb(us4 a, us4 b) {
  us8 r;
  r[0]=a[0]; r[1]=a[1]; r[2]=a[2]; r[3]=a[3];
  r[4]=b[0]; r[5]=b[1]; r[6]=b[2]; r[7]=b[3];
  return __builtin_bit_cast(bf8, r);
}

// ---------------- prep: x (f32 [16384][512]) -> bf16, chunk-swizzled ----------------
// storage: within each row, 16B chunk c stored at (c&~7)|((c&7)^(row&7))
__global__ __launch_bounds__(256) void k_convert_x(const float* __restrict__ x,
                                                   unsigned short* __restrict__ xb) {
  int c = blockIdx.x * 256 + threadIdx.x;   // 1,048,576 chunks
  int row = c >> 6, cl = c & 63;
  const float* s = x + ((size_t)row << 9) + (cl << 3);
  float4 a = *(const float4*)s;
  float4 b = *(const float4*)(s + 4);
  us8 o;
  o[0]=f2bf(a.x); o[1]=f2bf(a.y); o[2]=f2bf(a.z); o[3]=f2bf(a.w);
  o[4]=f2bf(b.x); o[5]=f2bf(b.y); o[6]=f2bf(b.z); o[7]=f2bf(b.w);
  int p = (cl & ~7) | ((cl & 7) ^ (row & 7));
  *(us8*)(xb + ((size_t)row << 9) + (p << 3)) = o;
}

// ------------- prep: W [512][N] f32 -> Wt [N][512] bf16, chunk-swizzled -------------
__global__ __launch_bounds__(256) void k_transpose_w(const float* __restrict__ W,
                                                     unsigned short* __restrict__ Wt, int N) {
  __shared__ float t[32][33];
  int k0 = blockIdx.x * 32, n0 = blockIdx.y * 32;
  int tx = threadIdx.x & 31, ty = threadIdx.x >> 5;
#pragma unroll
  for (int r = 0; r < 4; ++r)
    t[ty + r * 8][tx] = W[(size_t)(k0 + ty + r * 8) * N + n0 + tx];
  __syncthreads();
#pragma unroll
  for (int r = 0; r < 4; ++r) {
    int n = n0 + ty + r * 8, k = k0 + tx;
    int k2 = (k & ~63) | ((((k >> 3) & 7) ^ (n & 7)) << 3) | (k & 7);
    Wt[((size_t)n << 9) + k2] = f2bf(t[tx][ty + r * 8]);
  }
}

// ---------------- GEMM: C[M][col] = A[M][512] * Bt[col][512]^T + bias ----------------
// 128x128 tile, BK=64, 4 waves (2x2), each wave 64x64 via 4x4 16x16x32 mfma frags.
// EPI=0: QKV epilogue -> fragment-ordered Q/K/V (see k_attn); Q scaled by 0.125.
// EPI=1: f32 out + bias
template <int EPI>
__global__ __launch_bounds__(256, 2)
void k_gemm(const unsigned short* __restrict__ Ag, const unsigned short* __restrict__ Bg,
            const float* __restrict__ bias, float* __restrict__ Of,
            unsigned short* __restrict__ Oq, unsigned short* __restrict__ Ok,
            unsigned short* __restrict__ Ov) {
  __shared__ __align__(16) unsigned short lds[128 * 64 * 2];
  unsigned short* Al = lds;
  unsigned short* Bl = lds + 128 * 64;
  const int tid = threadIdx.x, wv = tid >> 6, lane = tid & 63, g = lane >> 4, cl = lane & 15;
  const int wm = wv >> 1, wn = wv & 1;
  const int row0 = blockIdx.x * 128, col0 = blockIdx.y * 128;
  f4 acc[4][4];
#pragma unroll
  for (int i = 0; i < 4; ++i)
#pragma unroll
    for (int j = 0; j < 4; ++j) acc[i][j] = (f4){0.f, 0.f, 0.f, 0.f};

  for (int kt = 0; kt < 8; ++kt) {
#pragma unroll
    for (int j = 0; j < 4; ++j) {
      int ci = wv * 4 + j;
      int gci = ci * 64 + lane;
      int r = gci >> 3, cc = gci & 7;
      gl_lds16(Ag + ((size_t)(row0 + r) << 9) + kt * 64 + cc * 8, Al + ci * 512);
      gl_lds16(Bg + ((size_t)(col0 + r) << 9) + kt * 64 + cc * 8, Bl + ci * 512);
    }
    __syncthreads();
#pragma unroll
    for (int kk = 0; kk < 2; ++kk) {
      bf8 af[4], bb[4];
#pragma unroll
      for (int mf = 0; mf < 4; ++mf) {
        int r = wm * 64 + mf * 16 + cl;
        int cc = (kk * 4 + g) ^ (r & 7);
        af[mf] = *(const bf8*)(Al + r * 64 + cc * 8);
      }
#pragma unroll
      for (int nf = 0; nf < 4; ++nf) {
        int r = wn * 64 + nf * 16 + cl;
        int cc = (kk * 4 + g) ^ (r & 7);
        bb[nf] = *(const bf8*)(Bl + r * 64 + cc * 8);
      }
#pragma unroll
      for (int mf = 0; mf < 4; ++mf)
#pragma unroll
        for (int nf = 0; nf < 4; ++nf)
          acc[mf][nf] = __builtin_amdgcn_mfma_f32_16x16x32_bf16(af[mf], bb[nf], acc[mf][nf], 0, 0, 0);
    }
    __syncthreads();
  }

  if (EPI == 1) {
#pragma unroll
    for (int nf = 0; nf < 4; ++nf) {
      int col = col0 + wn * 64 + nf * 16 + cl;
      float bv = bias[col];
#pragma unroll
      for (int mf = 0; mf < 4; ++mf) {
#pragma unroll
        for (int j = 0; j < 4; ++j) {
          int row = row0 + wm * 64 + mf * 16 + 4 * g + j;  // C/D: col=lane&15, row=4*(lane>>4)+reg
          Of[((size_t)row << 9) + col] = acc[mf][nf][j] + bv;
        }
      }
    }
  } else {
    const int which = col0 >> 9;   // block-uniform (col0 % 128 == 0)
#pragma unroll
    for (int nf = 0; nf < 4; ++nf) {
      int col = col0 + wn * 64 + nf * 16 + cl;
      float bv = bias[col];
      int d = col & 63, h = (col >> 6) & 7;
#pragma unroll
      for (int mf = 0; mf < 4; ++mf) {
        int row = row0 + wm * 64 + mf * 16 + 4 * g;   // j = 0 row
        int b = row >> 11, s = row & 2047;
        size_t fb = ((size_t)b * 8 + h) * 131072;     // per-(b,h) fragment array
        if (which == 0) {
          // Q frag: [q16][kk][lane=g*16+cl][8]; val = Q[s=q16*16+cl][d=kk*32+g*8+j]
#pragma unroll
          for (int j = 0; j < 4; ++j) {
            int ss = s + j;
            size_t off = fb + (size_t)((ss >> 4) * 1024 + (d >> 5) * 512 +
                                       (((d >> 3) & 3) * 16 + (ss & 15)) * 8 + (d & 7));
            Oq[off] = f2bf((acc[mf][nf][j] + bv) * 0.125f);   // fold softmax scale
          }
        } else if (which == 1) {
          // K frag: [kt][kk][ct][lane][8]; val = K[s=kt*64+ct*16+cl][d=kk*32+g*8+j]
#pragma unroll
          for (int j = 0; j < 4; ++j) {
            int ss = s + j;
            size_t off = fb + (size_t)((ss >> 6) * 4096 + (d >> 5) * 2048 + ((ss >> 4) & 3) * 512 +
                                       (((d >> 3) & 3) * 16 + (ss & 15)) * 8 + (d & 7));
            Ok[off] = f2bf(acc[mf][nf][j] + bv);
          }
        } else {
          // V frag: [kt][kk][ct][lane][8]; val = V[s=kt*64+kk*32+g*8+j][d=ct*16+cl]
          // j=0..3 are consecutive bytes (s&7 = 4*(g&1)+j) -> one us4 store
          us4 o;
#pragma unroll
          for (int j = 0; j < 4; ++j) o[j] = f2bf(acc[mf][nf][j] + bv);
          size_t off = fb + (size_t)((s >> 6) * 4096 + ((s >> 5) & 1) * 2048 + (d >> 4) * 512 +
                                     ((((s >> 3) & 3) * 16) + (d & 15)) * 8 + (s & 7));
          *(us4*)(Ov + off) = o;
        }
      }
    }
  }
}

// ------------------------------- flash attention --------------------------------
// block = (b, h, 64-row q tile); 4 waves x 16 q rows, fully independent (NO barriers).
// Q/K/V fragment loads are base + lane*16B -> fully coalesced (8 lines / 1KB).
// Only LDS: per-wave P-transpose buffer (same-wave DS ordering, no barrier).
__global__ __launch_bounds__(256, 3)
void k_attn(const unsigned short* __restrict__ Qf, const unsigned short* __restrict__ Kf,
            const unsigned short* __restrict__ Vf, const float* __restrict__ rel,
            unsigned short* __restrict__ AO) {
  __shared__ __align__(16) unsigned short Pl[4][16 * 68];
  const int tid = threadIdx.x, wv = tid >> 6, lane = tid & 63, g = lane >> 4, cl = lane & 15;
  // block-id swizzle: 8 batches sharing a rel_pos panel land on one XCD (bid%8 const)
  int bid = blockIdx.x;
  int glo = bid & 7, rest = bid >> 3;
  int b = rest & 7, ghi = rest >> 3;
  int grp = ghi * 8 + glo;
  int h = grp >> 5, qt = 31 - (grp & 31);        // big-first: long blocks dispatch early
  int qb = qt << 6;
  size_t fb = (((size_t)b << 3) + h) * 131072;
  const unsigned short* Qp = Qf + fb;
  const unsigned short* Kp = Kf + fb;
  const unsigned short* Vp = Vf + fb;
  const float* relp = rel + ((size_t)h << 22);
  const int qrb = qb + wv * 16;
  const int q16 = (qt << 2) + wv;

  bf8 qf[2];
#pragma unroll
  for (int kk = 0; kk < 2; ++kk)
    qf[kk] = *(const bf8*)(Qp + q16 * 1024 + kk * 512 + lane * 8);

  f4 oa[4];
  float mrun[4], lrun[4];
#pragma unroll
  for (int j = 0; j < 4; ++j) { mrun[j] = -1e30f; lrun[j] = 0.f; }
#pragma unroll
  for (int ct = 0; ct < 4; ++ct) oa[ct] = (f4){0.f, 0.f, 0.f, 0.f};

  unsigned short* pw = Pl[wv];

  for (int kt = 0; kt <= qt; ++kt) {
    int kb = kt << 6;
    const unsigned short* Kt = Kp + kt * 4096;
    const unsigned short* Vt = Vp + kt * 4096;
    // ---- coalesced fragment loads (1KB contiguous per instr) ----
    bf8 kf[2][4], vf[2][4];
#pragma unroll
    for (int kk = 0; kk < 2; ++kk)
#pragma unroll
      for (int ct = 0; ct < 4; ++ct) {
        kf[kk][ct] = *(const bf8*)(Kt + kk * 2048 + ct * 512 + lane * 8);
        vf[kk][ct] = *(const bf8*)(Vt + kk * 2048 + ct * 512 + lane * 8);
      }
    float rl[4][4];
    const float* rb = relp + ((size_t)(qrb + 4 * g) << 11) + kb + cl;
#pragma unroll
    for (int ct = 0; ct < 4; ++ct)
#pragma unroll
      for (int j = 0; j < 4; ++j)
        rl[ct][j] = rb[(j << 11) + ct * 16];

    // ---- QK^T ----
    f4 sa[4];
#pragma unroll
    for (int ct = 0; ct < 4; ++ct) sa[ct] = (f4){0.f, 0.f, 0.f, 0.f};
#pragma unroll
    for (int kk = 0; kk < 2; ++kk)
#pragma unroll
      for (int ct = 0; ct < 4; ++ct)
        sa[ct] = __builtin_amdgcn_mfma_f32_16x16x32_bf16(qf[kk], kf[kk][ct], sa[ct], 0, 0, 0);

    // rel_pos; causal mask only on the diagonal tile (interior: kcol<qb<=qrow always)
    if (kt == qt) {
#pragma unroll
      for (int ct = 0; ct < 4; ++ct) {
        int kcol = kb + ct * 16 + cl;
#pragma unroll
        for (int j = 0; j < 4; ++j) {
          int qrow = qrb + 4 * g + j;
          float sv = sa[ct][j] + rl[ct][j];
          sa[ct][j] = (kcol > qrow) ? -1e30f : sv;
        }
      }
    } else {
#pragma unroll
      for (int ct = 0; ct < 4; ++ct)
#pragma unroll
        for (int j = 0; j < 4; ++j) sa[ct][j] += rl[ct][j];
    }
    // wave-parallel online softmax (rows live in 16-lane groups)
    float al[4], mx[4];
#pragma unroll
    for (int j = 0; j < 4; ++j) {
      float m0 = fmaxf(fmaxf(sa[0][j], sa[1][j]), fmaxf(sa[2][j], sa[3][j]));
      m0 = fmaxf(m0, __shfl_xor(m0, 1, 16));
      m0 = fmaxf(m0, __shfl_xor(m0, 2, 16));
      m0 = fmaxf(m0, __shfl_xor(m0, 4, 16));
      m0 = fmaxf(m0, __shfl_xor(m0, 8, 16));
      float mn = fmaxf(mrun[j], m0);
      al[j] = __expf(mrun[j] - mn);
      mrun[j] = mn;
      mx[j] = mn;
    }
#pragma unroll
    for (int ct = 0; ct < 4; ++ct)
#pragma unroll
      for (int j = 0; j < 4; ++j) sa[ct][j] = __expf(sa[ct][j] - mx[j]);
#pragma unroll
    for (int j = 0; j < 4; ++j) {
      float rs = sa[0][j] + sa[1][j] + sa[2][j] + sa[3][j];
      rs += __shfl_xor(rs, 1, 16);
      rs += __shfl_xor(rs, 2, 16);
      rs += __shfl_xor(rs, 4, 16);
      rs += __shfl_xor(rs, 8, 16);
      lrun[j] = lrun[j] * al[j] + rs;
    }
#pragma unroll
    for (int ct = 0; ct < 4; ++ct) {
      oa[ct][0] *= al[0]; oa[ct][1] *= al[1]; oa[ct][2] *= al[2]; oa[ct][3] *= al[3];
    }
    // P -> bf16 -> per-wave LDS transpose (write C-layout, read A-layout).
    // Same-wave DS ops are in-order; no barrier needed.
#pragma unroll
    for (int ct = 0; ct < 4; ++ct)
#pragma unroll
      for (int j = 0; j < 4; ++j)
        pw[(4 * g + j) * 68 + ct * 16 + cl] = f2bf(sa[ct][j]);
    // PV: A = P[q=cl][k=kk*32+g*8+j], B = V frags (fragment-ordered)
#pragma unroll
    for (int kk = 0; kk < 2; ++kk) {
      us4 p0 = *(const us4*)(pw + cl * 68 + kk * 32 + g * 8);
      us4 p1 = *(const us4*)(pw + cl * 68 + kk * 32 + g * 8 + 4);
      bf8 pf = comb(p0, p1);
#pragma unroll
      for (int ct = 0; ct < 4; ++ct)
        oa[ct] = __builtin_amdgcn_mfma_f32_16x16x32_bf16(pf, vf[kk][ct], oa[ct], 0, 0, 0);
    }
  }
  // epilogue: O /= l, write bf16 [b][s][h*64+d] with chunk swizzle for out-GEMM staging
#pragma unroll
  for (int j = 0; j < 4; ++j) {
    float inv = 1.0f / lrun[j];
    int s = qrb + 4 * g + j;
#pragma unroll
    for (int ct = 0; ct < 4; ++ct) {
      int d = ct * 16 + cl;
      int d2 = (d & 7) | (((d >> 3) ^ (s & 7)) << 3);
      AO[(((size_t)b << 11) + s) * 512 + h * 64 + d2] = f2bf(oa[ct][j] * inv);
    }
  }
}

// ------------------------------------ launch ------------------------------------
extern "C" void kernel_launch(void* const* d_in, const int* in_sizes, int n_in,
                              void* d_out, int out_size, void* d_ws, size_t ws_size,
                              hipStream_t stream) {
  const float* x    = (const float*)d_in[0];
  const float* Wqkv = (const float*)d_in[1];
  const float* bqkv = (const float*)d_in[2];
  const float* Wout = (const float*)d_in[3];
  const float* bout = (const float*)d_in[4];
  const float* rel  = (const float*)d_in[5];
  float* out = (float*)d_out;

  unsigned short* Qw  = (unsigned short*)d_ws;
  unsigned short* Kw  = Qw  + 8388608;
  unsigned short* Vw  = Kw  + 8388608;
  unsigned short* AOw = Vw  + 8388608;
  unsigned short* Xb  = AOw + 8388608;
  unsigned short* WtQ = Xb  + 8388608;
  unsigned short* WtO = WtQ + 786432;

  k_convert_x<<<dim3(4096), dim3(256), 0, stream>>>(x, Xb);
  k_transpose_w<<<dim3(16, 48), dim3(256), 0, stream>>>(Wqkv, WtQ, 1536);
  k_transpose_w<<<dim3(16, 16), dim3(256), 0, stream>>>(Wout, WtO, 512);
  k_gemm<0><<<dim3(128, 12), dim3(256), 0, stream>>>(Xb, WtQ, bqkv, nullptr, Qw, Kw, Vw);
  k_attn<<<dim3(2048), dim3(256), 0, stream>>>(Qw, Kw, Vw, rel, AOw);
  k_gemm<1><<<dim3(128, 4), dim3(256), 0, stream>>>(AOw, WtO, bout, out, nullptr, nullptr, nullptr);
}